// Round 8
// baseline (32.587 us; speedup 1.0000x reference)
//
#include <hip/hip_runtime.h>

// SymPBC feature kernel for MI355X (v7: w-per-lane wave-uniform compute +
// full-S LDS obuf so each block writes its entire contiguous 120 KB output
// span in one ascending pass -> no partial-line write amplification).
//
// Round-7 evidence: v6 WRITE_SIZE = 93 MB vs 59 MB ideal (1.54x RFO-like
// amplification from 64 B store islands on misaligned 1888/944 B rows whose
// neighbors belong to other blocks). Fix: one block owns all s for its w-tile.
//
// Math (M=2 dual-pol collapses _triple's pol-swap into a sum over q):
//   B1 = sum_q E[w-n,q]*conj(E[w-m-n,q]);  B2 = sum_q E[w+n,q]*conj(E[w+m+n,q])
//   T1[p] = B1*E[w-m,p] + B2*E[w+m,p]
//   B3 = sum_q E[w-m,q]*conj(E[w-m-n,q]);  B4 = sum_q E[w+m,q]*conj(E[w+m+n,q])
//   T2[p] = B3*E[w-n,p] + B4*E[w+n,p]
//   F = w1*T1 + w2*T2;  w1 = 0.5 iff (m==0 && n==0);  w2 = (n > |m|)
// Output: out[b][w][p][s][c] float32, flat = (b*W+w)*472 + p*236 + s*2 + c.

constexpr int W = 16384;
constexpr int WMASK = W - 1;
constexpr int NB = 2;
constexpr int S = 118;
constexpr int HALO = 26;               // max |m+n|
constexpr int TW = 64;                 // w per block (== lanes per wave)
constexpr int ELD = TW + 2 * HALO;     // 116
constexpr int NT = 512;                // threads (8 waves)
constexpr int SPW = 15;                // s per wave (8*15 >= 118)
constexpr int NF4 = TW * S;            // 7552 float4 stores per block
constexpr int SITER = (NF4 + NT - 1) / NT;  // 15

struct C2 { float re, im; };

// s -> (m,n), Python iteration order. Group starts:
// m=-5:0  -4:1  -3:4  -2:10  -1:21  0:46  1:72  2:97  3:108  4:114  5:117
// s is wave-uniform here -> scalarizes.
__device__ inline void decode_s(int s, int& m, int& n) {
    const int g = (s>=1)+(s>=4)+(s>=10)+(s>=21)+(s>=46)
                + (s>=72)+(s>=97)+(s>=108)+(s>=114)+(s>=117);
    const int start = (s>=117)?117:(s>=114)?114:(s>=108)?108:(s>=97)?97:
                      (s>=72)?72:(s>=46)?46:(s>=21)?21:(s>=10)?10:
                      (s>=4)?4:(s>=1)?1:0;
    m = g - 5;
    const int am = (m < 0) ? -m : m;
    n = am + (s - start);
}

// bracket(Xa, Xb) = sum_q Xa_q * conj(Xb_q); X = (re0, im0, re1, im1)
__device__ inline C2 bracket(const float4 a, const float4 b) {
    C2 r;
    r.re = a.x*b.x + a.y*b.y + a.z*b.z + a.w*b.w;
    r.im = a.y*b.x - a.x*b.y + a.w*b.z - a.z*b.w;
    return r;
}

__device__ inline float4 compute_f(const float4 Am, const float4 Ap,
                                   const float4 An, const float4 Bn,
                                   const float4 Amn, const float4 Bmn,
                                   const float w1, const float w2) {
    const C2 B1 = bracket(An, Amn);
    const C2 B2 = bracket(Bn, Bmn);
    float r0 = B1.re*Am.x - B1.im*Am.y + B2.re*Ap.x - B2.im*Ap.y;
    float i0 = B1.re*Am.y + B1.im*Am.x + B2.re*Ap.y + B2.im*Ap.x;
    float r1 = B1.re*Am.z - B1.im*Am.w + B2.re*Ap.z - B2.im*Ap.w;
    float i1 = B1.re*Am.w + B1.im*Am.z + B2.re*Ap.w + B2.im*Ap.z;
    r0 *= w1; i0 *= w1; r1 *= w1; i1 *= w1;
    C2 B3 = bracket(Am, Amn);
    C2 B4 = bracket(Ap, Bmn);
    B3.re *= w2; B3.im *= w2; B4.re *= w2; B4.im *= w2;
    r0 += B3.re*An.x - B3.im*An.y + B4.re*Bn.x - B4.im*Bn.y;
    i0 += B3.re*An.y + B3.im*An.x + B4.re*Bn.y + B4.im*Bn.x;
    r1 += B3.re*An.z - B3.im*An.w + B4.re*Bn.z - B4.im*Bn.w;
    i1 += B3.re*An.w + B3.im*An.z + B4.re*Bn.w + B4.im*Bn.z;
    return make_float4(r0, i0, r1, i1);
}

__global__ __launch_bounds__(NT) void sympbc_kernel(
    const float* __restrict__ Er, const float* __restrict__ Ei,
    float* __restrict__ out)
{
    __shared__ float4 obuf[S][TW];   // 120,832 B; col index XOR-swizzled
    __shared__ float4 eld[ELD];      // 1,856 B

    const int tid = threadIdx.x;
    const int lane = tid & 63;
    const int wv = tid >> 6;         // wave 0..7
    const int b = blockIdx.y;
    const int tile0 = blockIdx.x * TW;

    // Stage E window: interleaved complex dual-pol (re0, im0, re1, im1).
    if (tid < ELD) {
        const int gw = (tile0 - HALO + tid) & WMASK;
        const size_t gi = ((size_t)b * W + gw) * 2;
        const float2 r = *reinterpret_cast<const float2*>(Er + gi);
        const float2 i = *reinterpret_cast<const float2*>(Ei + gi);
        eld[tid] = make_float4(r.x, i.x, r.y, i.y);
    }
    __syncthreads();

    // ---- compute: wave wv owns s in [wv*15, wv*15+15) ∩ [0,118)
    const int ci = HALO + lane;
    const float4 Eself = eld[ci];

    #pragma unroll
    for (int k = 0; k < SPW; ++k) {
        const int s = wv * SPW + k;            // wave-uniform
        if (s < S) {
            int m, n;
            decode_s(s, m, n);
            const int am = (m < 0) ? -m : m;
            const int mn = m + n;
            const float w1 = (s == 46) ? 0.5f : 1.0f;   // (m,n)==(0,0)
            const float w2 = (n > am) ? 1.0f : 0.0f;

            const float4 An = eld[ci - n];
            const float4 Bn = eld[ci + n];
            float4 Am, Ap, Amn, Bmn;
            if (m == 0) {                       // uniform branch (26 of 118)
                Am = Eself; Ap = Eself; Amn = An; Bmn = Bn;
            } else {
                Am  = eld[ci - m];  Ap  = eld[ci + m];
                Amn = eld[ci - mn]; Bmn = eld[ci + mn];
            }
            obuf[s][lane ^ ((s >> 1) & 7)] =
                compute_f(Am, Ap, An, Bn, Amn, Bmn, w1, w2);
        }
    }
    __syncthreads();

    // ---- store: whole 120,832 B block span, ascending, fully coalesced.
    // float4 slot f in [0,7552): w = f/118, r = f%118, p = r>=59, j = r%59.
    // address (floats): (b*W + tile0 + w)*472 + p*236 + j*4
    // payload: s=2j and s=2j+1 (re,im) for pol p.
    const size_t base = ((size_t)b * W + tile0) * 472;
    #pragma unroll
    for (int k = 0; k < SITER; ++k) {
        const int f = k * NT + tid;
        if (f < NF4) {
            const int w = (f * 8887) >> 20;     // f/118, exact for f<7552
            const int r = f - w * 118;
            const int p = (r >= 59) ? 1 : 0;
            const int j = r - 59 * p;
            const int xk = j & 7;
            const float4 F0 = obuf[2 * j][w ^ xk];
            const float4 F1 = obuf[2 * j + 1][w ^ xk];
            const float4 v = p ? make_float4(F0.z, F0.w, F1.z, F1.w)
                               : make_float4(F0.x, F0.y, F1.x, F1.y);
            *reinterpret_cast<float4*>(out + base + (size_t)w * 472
                                       + p * 236 + j * 4) = v;
        }
    }
}

extern "C" void kernel_launch(void* const* d_in, const int* in_sizes, int n_in,
                              void* d_out, int out_size, void* d_ws, size_t ws_size,
                              hipStream_t stream) {
    const float* Er = (const float*)d_in[0];
    const float* Ei = (const float*)d_in[1];
    float* out = (float*)d_out;
    dim3 grid(W / TW, NB);
    sympbc_kernel<<<grid, dim3(NT), 0, stream>>>(Er, Ei, out);
}

// Round 9
// 24.368 us; speedup vs baseline: 1.3373x; 1.3373x over previous
//
#include <hip/hip_runtime.h>

// SymPBC feature kernel for MI355X (v8).
// Design constraints proven by rounds 1-8:
//  - block must own its FULL contiguous output span (16 w x 1888 B) -> exact
//    HBM writes (v6 measured 93 MB vs 59 MB ideal with split-s blocks);
//  - LDS operand reads must be group-uniform (s-per-lane scatter = multi-way
//    bank conflicts ~= the v1/v2 20 us wall);
//  - 8 blocks/CU (32 waves) for latency hiding (v3/v7's 8 waves/CU lost).
// v8: TW=16, 256 thr, S in 4 chunks {30,30,30,28} via 8.2 KB obuf.
//   compute: lane -> (w = lane&15, slot = lane>>4); slot+wave pick s.
//   store:   ascending walk of the span, magic-mul indexing, float4/lane.
//
// Math (M=2 dual-pol collapses _triple's pol-swap into a sum over q):
//   B1 = sum_q E[w-n,q]*conj(E[w-m-n,q]);  B2 = sum_q E[w+n,q]*conj(E[w+m+n,q])
//   T1[p] = B1*E[w-m,p] + B2*E[w+m,p]
//   B3 = sum_q E[w-m,q]*conj(E[w-m-n,q]);  B4 = sum_q E[w+m,q]*conj(E[w+m+n,q])
//   T2[p] = B3*E[w-n,p] + B4*E[w+n,p]
//   F = w1*T1 + w2*T2;  w1 = 0.5 iff (m==0 && n==0);  w2 = (n > |m|)
// Output: out[b][w][p][s][c] float32, flat = (b*W+w)*472 + p*236 + s*2 + c.

constexpr int W = 16384;
constexpr int WMASK = W - 1;
constexpr int NB = 2;
constexpr int S = 118;
constexpr int HALO = 26;               // max |m+n|
constexpr int TW = 16;                 // w per block
constexpr int ELD = TW + 2 * HALO;     // 68
constexpr int NT = 256;                // 4 waves
constexpr int CH = 30;                 // nominal s per chunk (last = 28)

struct C2 { float re, im; };

// s -> (m,n), Python iteration order. Group starts:
// m=-5:0  -4:1  -3:4  -2:10  -1:21  0:46  1:72  2:97  3:108  4:114  5:117
__device__ inline void decode_s(int s, int& m, int& n) {
    const int g = (s>=1)+(s>=4)+(s>=10)+(s>=21)+(s>=46)
                + (s>=72)+(s>=97)+(s>=108)+(s>=114)+(s>=117);
    const int start = (s>=117)?117:(s>=114)?114:(s>=108)?108:(s>=97)?97:
                      (s>=72)?72:(s>=46)?46:(s>=21)?21:(s>=10)?10:
                      (s>=4)?4:(s>=1)?1:0;
    m = g - 5;
    const int am = (m < 0) ? -m : m;
    n = am + (s - start);
}

// bracket(Xa, Xb) = sum_q Xa_q * conj(Xb_q); X = (re0, im0, re1, im1)
__device__ inline C2 bracket(const float4 a, const float4 b) {
    C2 r;
    r.re = a.x*b.x + a.y*b.y + a.z*b.z + a.w*b.w;
    r.im = a.y*b.x - a.x*b.y + a.w*b.z - a.z*b.w;
    return r;
}

__device__ inline float4 compute_f(const float4 Am, const float4 Ap,
                                   const float4 An, const float4 Bn,
                                   const float4 Amn, const float4 Bmn,
                                   const float w1, const float w2) {
    const C2 B1 = bracket(An, Amn);
    const C2 B2 = bracket(Bn, Bmn);
    float r0 = B1.re*Am.x - B1.im*Am.y + B2.re*Ap.x - B2.im*Ap.y;
    float i0 = B1.re*Am.y + B1.im*Am.x + B2.re*Ap.y + B2.im*Ap.x;
    float r1 = B1.re*Am.z - B1.im*Am.w + B2.re*Ap.z - B2.im*Ap.w;
    float i1 = B1.re*Am.w + B1.im*Am.z + B2.re*Ap.w + B2.im*Ap.z;
    r0 *= w1; i0 *= w1; r1 *= w1; i1 *= w1;
    C2 B3 = bracket(Am, Amn);
    C2 B4 = bracket(Ap, Bmn);
    B3.re *= w2; B3.im *= w2; B4.re *= w2; B4.im *= w2;
    r0 += B3.re*An.x - B3.im*An.y + B4.re*Bn.x - B4.im*Bn.y;
    i0 += B3.re*An.y + B3.im*An.x + B4.re*Bn.y + B4.im*Bn.x;
    r1 += B3.re*An.z - B3.im*An.w + B4.re*Bn.z - B4.im*Bn.w;
    i1 += B3.re*An.w + B3.im*An.z + B4.re*Bn.w + B4.im*Bn.z;
    return make_float4(r0, i0, r1, i1);
}

__global__ __launch_bounds__(NT) void sympbc_kernel(
    const float* __restrict__ Er, const float* __restrict__ Ei,
    float* __restrict__ out)
{
    __shared__ float4 eld[ELD];            // 1,088 B
    __shared__ float4 obuf[CH][TW + 1];    // 8,160 B; rows: evens [0,NH) odds [NH,cnt)

    const int tid = threadIdx.x;
    const int b = blockIdx.y;
    const int tile0 = blockIdx.x * TW;

    // Stage E window: interleaved complex dual-pol (re0, im0, re1, im1).
    if (tid < ELD) {
        const int gw = (tile0 - HALO + tid) & WMASK;
        const size_t gi = ((size_t)b * W + gw) * 2;
        const float2 r = *reinterpret_cast<const float2*>(Er + gi);
        const float2 i = *reinterpret_cast<const float2*>(Ei + gi);
        eld[tid] = make_float4(r.x, i.x, r.y, i.y);
    }
    __syncthreads();

    const int w  = tid & 15;               // w within tile
    const int hw = tid >> 4;               // 0..15: (wave, slot) -> s-run id
    const int ci = HALO + w;
    const float4 Eself = eld[ci];
    const size_t base = ((size_t)b * W + tile0) * 472;

    #pragma unroll
    for (int c = 0; c < 4; ++c) {
        const int s_lo = CH * c;
        const int cnt = (c == 3) ? 28 : 30;
        const int NH = cnt >> 1;

        // ---- compute: run hw covers s_local = 2*hw, 2*hw+1
        #pragma unroll
        for (int u = 0; u < 2; ++u) {
            const int sl = 2 * hw + u;
            if (sl < cnt) {
                const int s = s_lo + sl;
                int m, n;
                decode_s(s, m, n);
                const int am = (m < 0) ? -m : m;
                const int mn = m + n;
                const float w1 = (s == 46) ? 0.5f : 1.0f;   // (m,n)==(0,0)
                const float w2 = (n > am) ? 1.0f : 0.0f;

                const float4 An = eld[ci - n];
                const float4 Bn = eld[ci + n];
                float4 Am, Ap, Amn, Bmn;
                if (m == 0) {               // 26 of 118: only 2 reads
                    Am = Eself; Ap = Eself; Amn = An; Bmn = Bn;
                } else {
                    Am  = eld[ci - m];  Ap  = eld[ci + m];
                    Amn = eld[ci - mn]; Bmn = eld[ci + mn];
                }
                obuf[hw + NH * u][w] =
                    compute_f(Am, Ap, An, Bn, Amn, Bmn, w1, w2);
            }
        }
        __syncthreads();

        // ---- store: ascending walk of this chunk's slice of the span.
        // f in [0, 16*cnt): ww = f/cnt, r = f%cnt, p = r>=NH, jl = r-p*NH
        // addr floats: ww*472 + p*236 + (s_lo/2 + jl)*4
        const int magic = (cnt == 30) ? 1093 : 1171;   // ceil(2^15/cnt)
        const int NF = TW * cnt;
        #pragma unroll
        for (int it = 0; it < 2; ++it) {
            const int f = it * NT + tid;
            if (f < NF) {
                const int ww = (f * magic) >> 15;
                const int r  = f - ww * cnt;
                const int p  = (r >= NH) ? 1 : 0;
                const int jl = r - p * NH;
                const float4 F0 = obuf[jl][ww];        // s = s_lo + 2*jl
                const float4 F1 = obuf[NH + jl][ww];   // s = s_lo + 2*jl + 1
                const float4 v = p ? make_float4(F0.z, F0.w, F1.z, F1.w)
                                   : make_float4(F0.x, F0.y, F1.x, F1.y);
                *reinterpret_cast<float4*>(
                    out + base + (size_t)ww * 472 + p * 236
                        + (s_lo / 2 + jl) * 4) = v;
            }
        }
        __syncthreads();
    }
}

extern "C" void kernel_launch(void* const* d_in, const int* in_sizes, int n_in,
                              void* d_out, int out_size, void* d_ws, size_t ws_size,
                              hipStream_t stream) {
    const float* Er = (const float*)d_in[0];
    const float* Ei = (const float*)d_in[1];
    float* out = (float*)d_out;
    dim3 grid(W / TW, NB);
    sympbc_kernel<<<grid, dim3(NT), 0, stream>>>(Er, Ei, out);
}